// Round 6
// baseline (251.282 us; speedup 1.0000x reference)
//
#include <hip/hip_runtime.h>

typedef unsigned short u16;
typedef short short8 __attribute__((ext_vector_type(8)));
typedef unsigned short ushort8 __attribute__((ext_vector_type(8)));
typedef float floatx16 __attribute__((ext_vector_type(16)));

// ---- sizes (ushort units unless noted) ----
// masked/t1 layout: [n 8][cg 16][half 2][r 66][c 66][j 8] bf16 (padded, swizzled)
#define PLANE8   34848          // 66*66*8
#define NSTRIDE  1115136        // 16*2*PLANE8
// t2 layout: [n 8][co 256][pix 4096] bf16 (plane, matches preds_T flat index)
// Wsw layout: [cg 16][ct 4][d 1152][j 8] bf16 ; d = tap*128 + sc*64 + cihalf*32 + colow
// part layout: [slot 96][bid 512] fp32 ; slot: 0..7 pp, 8..15 tt, 16..79 pt(i*8+j)

__device__ __forceinline__ u16 f2b(float f) {
  unsigned u = __builtin_bit_cast(unsigned, f);
  return (u16)((u + 0x7FFFu + ((u >> 16) & 1u)) >> 16);
}
__device__ __forceinline__ float b2f(u16 b) {
  return __builtin_bit_cast(float, ((unsigned)b) << 16);
}

typedef const __attribute__((address_space(1))) unsigned int* gptr_t;
typedef __attribute__((address_space(3))) unsigned int* sptr_t;

// ---------------------------------------------------------------------------
// k1: 1x1 conv + checkerboard mask (fp32 math), swizzled bf16 out.
// ---------------------------------------------------------------------------
__global__ __launch_bounds__(256) void k1(const float* __restrict__ pS,
    const float* __restrict__ Wa, const float* __restrict__ ba,
    u16* __restrict__ mk)
{
  __shared__ float wl[1024];   // [ci 128][k 8]
  int b = blockIdx.x;
  int pb = b & 3, cog = (b >> 2) & 31, n = b >> 7;
  int t = threadIdx.x;
  for (int i = t; i < 1024; i += 256) {
    int ci = i >> 3, k = i & 7;
    wl[i] = Wa[cog * 1024 + k * 128 + ci];
  }
  __syncthreads();

  int pix0 = pb * 1024 + t * 4;
  const float* sp = pS + (((size_t)n * 128) << 12) + pix0;

  float acc[8][4];
  #pragma unroll
  for (int k = 0; k < 8; ++k)
    #pragma unroll
    for (int q = 0; q < 4; ++q) acc[k][q] = 0.f;

  for (int ci = 0; ci < 128; ++ci) {
    float4 s = *(const float4*)(sp + ((size_t)ci << 12));
    float4 w0 = *(const float4*)(wl + ci * 8);
    float4 w1 = *(const float4*)(wl + ci * 8 + 4);
    float wv[8] = {w0.x, w0.y, w0.z, w0.w, w1.x, w1.y, w1.z, w1.w};
    #pragma unroll
    for (int k = 0; k < 8; ++k) {
      acc[k][0] += s.x * wv[k];
      acc[k][1] += s.y * wv[k];
      acc[k][2] += s.z * wv[k];
      acc[k][3] += s.w * wv[k];
    }
  }

  float bias[8];
  #pragma unroll
  for (int k = 0; k < 8; ++k) bias[k] = ba[cog * 8 + k];
  int h = pix0 >> 6, w = pix0 & 63;
  u16* base = mk + (size_t)n * NSTRIDE + (size_t)cog * PLANE8
              + ((size_t)(h + 1) * 66 + (w + 1)) * 8;
  #pragma unroll
  for (int q = 0; q < 4; ++q) {
    float msk = (float)((h + w + q) & 1);
    short8 v;
    #pragma unroll
    for (int k = 0; k < 8; ++k)
      v[k] = (short)f2b((acc[k][q] + bias[k]) * msk);
    *(short8*)(base + q * 8) = v;
  }
}

// ---------------------------------------------------------------------------
// kwc2: convert/swizzle BOTH 3x3 weight tensors in one launch (grid 576).
// ---------------------------------------------------------------------------
__global__ __launch_bounds__(256) void kwc2(const float* __restrict__ W1,
    const float* __restrict__ W2, u16* __restrict__ D1, u16* __restrict__ D2)
{
  int cid = blockIdx.x * 256 + threadIdx.x;        // < 147456
  const float* W = W1; u16* D = D1;
  if (cid >= 73728) { W = W2; D = D2; cid -= 73728; }
  int d = cid % 1152, ctcg = cid / 1152;
  int ct = ctcg & 3, cg = ctcg >> 2;
  int colow = d & 31, cihalf = (d >> 5) & 1, sc = (d >> 6) & 1, tap = d >> 7;
  int co = ct * 64 + sc * 32 + colow;
  short8 v;
  #pragma unroll
  for (int jj = 0; jj < 8; ++jj) {
    int ci = cg * 16 + cihalf * 8 + jj;
    v[jj] = (short)f2b(W[((size_t)(co * 256 + ci)) * 9 + tap]);
  }
  *(short8*)&D[(size_t)cid * 8] = v;
}

// ---------------------------------------------------------------------------
// kconv: 3x3 conv 256->256, bf16 MFMA implicit GEMM.
// grid 512 = n(8) x ct(4) x rowtile(16); block 128 thr = 2 waves.
// Wave: 64co x 2rows x 64col. B-frags global->VGPR (no LDS), software-
// pipelined 1 cg ahead. Input LDS double-buffered, ONE barrier per cg.
// A-reads: 4 rows loaded once per (dc,ch), shared across dr -> 24/iter.
// MODE 0: +bias, relu, swizzled padded store (gen1)
// MODE 1: +bias, LDS-transpose, plane store [n][co][4096] (gen2)
// ---------------------------------------------------------------------------
template <int MODE>
__global__ __launch_bounds__(128, 1) void kconv(
    const u16* __restrict__ IN, const u16* __restrict__ WS,
    const float* __restrict__ bg, u16* __restrict__ OUT)
{
  __shared__ __align__(16) u16 Lin[2][896 * 8];   // 2 x 14336 B

  int b = blockIdx.x;
  int rt = b & 15, ct = (b >> 4) & 3, n = b >> 6;
  int h0 = rt * 4;
  int t = threadIdx.x;
  int wid = t >> 6, lane = t & 63;
  int hf = lane >> 5, ml = lane & 31;

  // Input staging: 14 segs (2 halves x 7), 7 per wave. Tail over-read of s=6
  // stays inside d_ws; garbage LDS chunks (>=396 per half) never read.
  int in_goff[7], lds_off[7];
  #pragma unroll
  for (int k = 0; k < 7; ++k) {
    int seg = 2 * k + wid;
    int half = seg >= 7 ? 1 : 0;
    int s = seg - half * 7;
    in_goff[k] = half * PLANE8 + (h0 * 66 + s * 64 + lane) * 8;
    lds_off[k] = (half * 448 + s * 64) * 8;
  }

  const u16* inb = IN + (size_t)n * NSTRIDE;
  const u16* wg  = WS + (size_t)ct * 9216;   // 1152 chunks * 8

  floatx16 acc[2][2][2];   // [row r][colhalf ch][co-sub q]
  #pragma unroll
  for (int r = 0; r < 2; ++r)
    #pragma unroll
    for (int ch = 0; ch < 2; ++ch)
      #pragma unroll
      for (int q = 0; q < 2; ++q)
        #pragma unroll
        for (int i = 0; i < 16; ++i) acc[r][ch][q][i] = 0.f;

  // prologue: stage cg=0 input, load cg=0 B-frags
  #pragma unroll
  for (int k = 0; k < 7; ++k)
    __builtin_amdgcn_global_load_lds((gptr_t)(const void*)(inb + in_goff[k]),
                                     (sptr_t)(void*)(&Lin[0][0] + lds_off[k]), 16, 0, 0);
  short8 Bq[2][9][2];
  #pragma unroll
  for (int tap = 0; tap < 9; ++tap)
    #pragma unroll
    for (int q = 0; q < 2; ++q)
      Bq[0][tap][q] = *(const short8*)(wg + (size_t)(tap * 128 + q * 64 + lane) * 8);

  #pragma unroll 2
  for (int cg = 0; cg < 16; ++cg) {
    int pc = cg & 1;
    __syncthreads();   // drains stage(cg) [+ earlier B loads, already consumed]
    if (cg < 15) {
      #pragma unroll
      for (int k = 0; k < 7; ++k)
        __builtin_amdgcn_global_load_lds(
            (gptr_t)(const void*)(inb + (size_t)(cg + 1) * 69696 + in_goff[k]),
            (sptr_t)(void*)(&Lin[pc ^ 1][0] + lds_off[k]), 16, 0, 0);
      #pragma unroll
      for (int tap = 0; tap < 9; ++tap)
        #pragma unroll
        for (int q = 0; q < 2; ++q)
          Bq[pc ^ 1][tap][q] = *(const short8*)(
              wg + (size_t)((cg + 1) * 4608 + tap * 128 + q * 64 + lane) * 8);
    }
    const short8* LV = (const short8*)Lin[pc];
    #pragma unroll
    for (int dc = 0; dc < 3; ++dc) {
      #pragma unroll
      for (int ch = 0; ch < 2; ++ch) {
        short8 fr[4];
        #pragma unroll
        for (int rr = 0; rr < 4; ++rr)
          fr[rr] = LV[hf * 448 + (2 * wid + rr) * 66 + ch * 32 + ml + dc];
        #pragma unroll
        for (int dr = 0; dr < 3; ++dr) {
          #pragma unroll
          for (int q = 0; q < 2; ++q) {
            short8 w = Bq[pc][dr * 3 + dc][q];
            acc[0][ch][q] = __builtin_amdgcn_mfma_f32_32x32x16_bf16(fr[dr],     w, acc[0][ch][q], 0, 0, 0);
            acc[1][ch][q] = __builtin_amdgcn_mfma_f32_32x32x16_bf16(fr[dr + 1], w, acc[1][ch][q], 0, 0, 0);
          }
        }
      }
    }
  }

  float bias0 = bg[ct * 64 + ml];        // q=0
  float bias1 = bg[ct * 64 + 32 + ml];   // q=1

  if (MODE == 0) {
    // swizzled padded store; co = ct*64 + q*32 + ml, col p = ch*32 + m,
    // row o = h0 + 2*wid + r.
    u16* ob = OUT + (size_t)n * NSTRIDE;
    int co0 = ct * 64 + ml, co1 = co0 + 32;
    int cb0 = ((co0 >> 4) * 2 + ((co0 >> 3) & 1)) * PLANE8 + (co0 & 7);
    int cb1 = ((co1 >> 4) * 2 + ((co1 >> 3) & 1)) * PLANE8 + (co1 & 7);
    #pragma unroll
    for (int r = 0; r < 2; ++r) {
      int rowoff = (h0 + 2 * wid + r + 1) * 66 + 1;
      #pragma unroll
      for (int reg = 0; reg < 16; ++reg) {
        int m = (reg & 3) + 8 * (reg >> 2) + 4 * hf;
        float v;
        v = acc[r][0][0][reg] + bias0; v = fmaxf(v, 0.f); ob[cb0 + (rowoff + m) * 8] = f2b(v);
        v = acc[r][0][1][reg] + bias1; v = fmaxf(v, 0.f); ob[cb1 + (rowoff + m) * 8] = f2b(v);
        v = acc[r][1][0][reg] + bias0; v = fmaxf(v, 0.f); ob[cb0 + (rowoff + 32 + m) * 8] = f2b(v);
        v = acc[r][1][1][reg] + bias1; v = fmaxf(v, 0.f); ob[cb1 + (rowoff + 32 + m) * 8] = f2b(v);
      }
    }
  } else {
    // LDS transpose -> plane [n][co][4096]; wave wid uses its own Lin buffer.
    u16* plane = &Lin[wid][0];   // 64co x 68 stride, 8704 B < 14336 B
    #pragma unroll
    for (int r = 0; r < 2; ++r) {
      __syncthreads();
      #pragma unroll
      for (int reg = 0; reg < 16; ++reg) {
        int m = (reg & 3) + 8 * (reg >> 2) + 4 * hf;
        plane[ml * 68 + m]              = f2b(acc[r][0][0][reg] + bias0);
        plane[(32 + ml) * 68 + m]       = f2b(acc[r][0][1][reg] + bias1);
        plane[ml * 68 + 32 + m]         = f2b(acc[r][1][0][reg] + bias0);
        plane[(32 + ml) * 68 + 32 + m]  = f2b(acc[r][1][1][reg] + bias1);
      }
      __syncthreads();
      const u16* row = plane + lane * 68;   // co_local = lane
      __align__(16) u16 tmp[64];
      #pragma unroll
      for (int k2 = 0; k2 < 16; ++k2)
        *(ushort4*)(tmp + k2 * 4) = *(const ushort4*)(row + k2 * 4);
      u16* gdst = OUT + (size_t)n * 1048576 + (size_t)(ct * 64 + lane) * 4096
                  + (h0 + 2 * wid + r) * 64;
      #pragma unroll
      for (int k2 = 0; k2 < 8; ++k2)
        *(ushort8*)(gdst + k2 * 8) = *(const ushort8*)(tmp + k2 * 8);
    }
  }
}

// ---------------------------------------------------------------------------
// kbmc: fused reduction over d (plane layouts match). No atomics.
// ---------------------------------------------------------------------------
__global__ __launch_bounds__(256) void kbmc(const u16* __restrict__ t2,
    const float* __restrict__ pT, float* __restrict__ part)
{
  int t = threadIdx.x, lane = t & 63, role = t >> 6;
  int ih = role >> 1, nh = role & 1;
  int bid = blockIdx.x;

  float pt[4][4], pp[4], tt[4];
  #pragma unroll
  for (int i = 0; i < 4; ++i) {
    pp[i] = 0.f; tt[i] = 0.f;
    #pragma unroll
    for (int j = 0; j < 4; ++j) pt[i][j] = 0.f;
  }

  const float* pb = pT + ((size_t)ih * 4) * 1048576;
  const u16*   tb = t2 + ((size_t)nh * 4) * 1048576;

  for (int k = 0; k < 8; ++k) {
    size_t d0 = ((size_t)(bid * 512 + k * 64 + lane)) * 4;
    float4 p[4], tf[4];
    #pragma unroll
    for (int i = 0; i < 4; ++i)
      p[i] = *(const float4*)(pb + (size_t)i * 1048576 + d0);
    #pragma unroll
    for (int j = 0; j < 4; ++j) {
      ushort4 tv = *(const ushort4*)(tb + (size_t)j * 1048576 + d0);
      tf[j] = make_float4(b2f(tv.x), b2f(tv.y), b2f(tv.z), b2f(tv.w));
    }
    if (nh == 0) {
      #pragma unroll
      for (int i = 0; i < 4; ++i)
        pp[i] += p[i].x * p[i].x + p[i].y * p[i].y + p[i].z * p[i].z + p[i].w * p[i].w;
    }
    if (ih == 0) {
      #pragma unroll
      for (int j = 0; j < 4; ++j)
        tt[j] += tf[j].x * tf[j].x + tf[j].y * tf[j].y + tf[j].z * tf[j].z + tf[j].w * tf[j].w;
    }
    #pragma unroll
    for (int i = 0; i < 4; ++i)
      #pragma unroll
      for (int j = 0; j < 4; ++j)
        pt[i][j] += p[i].x * tf[j].x + p[i].y * tf[j].y
                  + p[i].z * tf[j].z + p[i].w * tf[j].w;
  }

  #pragma unroll
  for (int m = 1; m < 64; m <<= 1) {
    #pragma unroll
    for (int i = 0; i < 4; ++i) {
      pp[i] += __shfl_xor(pp[i], m);
      tt[i] += __shfl_xor(tt[i], m);
      #pragma unroll
      for (int j = 0; j < 4; ++j) pt[i][j] += __shfl_xor(pt[i][j], m);
    }
  }
  if (lane == 0) {
    #pragma unroll
    for (int i = 0; i < 4; ++i)
      #pragma unroll
      for (int j = 0; j < 4; ++j)
        part[(size_t)(16 + (ih * 4 + i) * 8 + (nh * 4 + j)) * 512 + bid] = pt[i][j];
    if (nh == 0) {
      #pragma unroll
      for (int i = 0; i < 4; ++i) part[(size_t)(ih * 4 + i) * 512 + bid] = pp[i];
    }
    if (ih == 0) {
      #pragma unroll
      for (int j = 0; j < 4; ++j) part[(size_t)(8 + nh * 4 + j) * 512 + bid] = tt[j];
    }
  }
}

// ---------------------------------------------------------------------------
// kred: 80 blocks x 256 threads; block s reduces part[s][0..512) -> accums[s].
// ---------------------------------------------------------------------------
__global__ __launch_bounds__(256) void kred(const float* __restrict__ part,
                                            float* __restrict__ accums)
{
  __shared__ float r4[4];
  int s = blockIdx.x, t = threadIdx.x, lane = t & 63, wid = t >> 6;
  float v = part[(size_t)s * 512 + t] + part[(size_t)s * 512 + 256 + t];
  #pragma unroll
  for (int m = 1; m < 64; m <<= 1) v += __shfl_xor(v, m);
  if (lane == 0) r4[wid] = v;
  __syncthreads();
  if (t == 0) accums[s] = r4[0] + r4[1] + r4[2] + r4[3];
}

// ---------------------------------------------------------------------------
// k4: 8x8 logsumexp finisher, one lane per (i,j) logit; shuffle reductions.
// ---------------------------------------------------------------------------
__global__ void k4_final(const float* __restrict__ accums, float* __restrict__ out)
{
  int t = threadIdx.x;           // 64 threads, lane = i*8 + j
  int i = t >> 3, j = t & 7;
  double pp = accums[i];
  double tt = accums[8 + j];
  double pt = accums[16 + i * 8 + j];
  double logit = -0.5 * (pp + tt - 2.0 * pt) / 64.0;
  double m = logit;
  #pragma unroll
  for (int s = 1; s < 8; s <<= 1) {
    double o = __shfl_xor(m, s);
    m = o > m ? o : m;
  }
  double e = exp(logit - m);
  #pragma unroll
  for (int s = 1; s < 8; s <<= 1) e += __shfl_xor(e, s);
  double lse = m + log(e);
  double term = (j == i) ? (lse - logit) : 0.0;
  #pragma unroll
  for (int s = 1; s < 64; s <<= 1) term += __shfl_xor(term, s);
  if (t == 0) {
    double ce = term / 8.0;
    out[0] = (float)(ce * (2.0 * 64.0) / 8.0 * 2e-05);
  }
}

// ---------------------------------------------------------------------------
extern "C" void kernel_launch(void* const* d_in, const int* in_sizes, int n_in,
                              void* d_out, int out_size, void* d_ws, size_t ws_size,
                              hipStream_t stream)
{
  const float* preds_S = (const float*)d_in[0];
  const float* preds_T = (const float*)d_in[1];
  const float* W_align = (const float*)d_in[2];
  const float* b_align = (const float*)d_in[3];
  const float* W_gen1  = (const float*)d_in[4];
  const float* b_gen1  = (const float*)d_in[5];
  const float* W_gen2  = (const float*)d_in[6];
  const float* b_gen2  = (const float*)d_in[7];
  float* out = (float*)d_out;

  char* wsb = (char*)d_ws;
  u16* masked = (u16*)wsb;                          // 17,842,176 B (swizzled padded)
  u16* t1     = (u16*)(wsb + 17842176);             // 17,842,176 B (swizzled padded)
  u16* t2p    = (u16*)(wsb + 35684352);             // 16,777,216 B (plane [n][co][pix])
  u16* Wsw1   = (u16*)(wsb + 52461568);             //  1,179,648 B
  u16* Wsw2   = (u16*)(wsb + 53641216);             //  1,179,648 B
  float* part   = (float*)(wsb + 54820864);         //    196,608 B [96][512]
  float* accums = (float*)(wsb + 55017472);         //        384 B

  hipMemsetAsync(wsb, 0, 35684352, stream);         // masked + t1 (zero borders)

  kwc2<<<576, 256, 0, stream>>>(W_gen1, W_gen2, Wsw1, Wsw2);
  k1<<<1024, 256, 0, stream>>>(preds_S, W_align, b_align, masked);
  kconv<0><<<512, 128, 0, stream>>>(masked, Wsw1, b_gen1, t1);    // relu -> t1
  kconv<1><<<512, 128, 0, stream>>>(t1, Wsw2, b_gen2, t2p);       // plane -> t2
  kbmc<<<512, 256, 0, stream>>>(t2p, preds_T, part);
  kred<<<80, 256, 0, stream>>>(part, accums);
  k4_final<<<1, 64, 0, stream>>>(accums, out);
}

// Round 7
// 242.345 us; speedup vs baseline: 1.0369x; 1.0369x over previous
//
#include <hip/hip_runtime.h>

typedef unsigned short u16;
typedef short short8 __attribute__((ext_vector_type(8)));
typedef unsigned short ushort8 __attribute__((ext_vector_type(8)));
typedef float floatx16 __attribute__((ext_vector_type(16)));

// ---- sizes (ushort units unless noted) ----
// masked/t1 layout: [n 8][cg 16][half 2][r 66][c 66][j 8] bf16 (padded, swizzled)
// masked and t1 are contiguous: plane p in [0,512), addr = masked + p*PLANE8.
#define PLANE8   34848          // 66*66*8
#define NSTRIDE  1115136        // 16*2*PLANE8
// t2 layout: [n 8][co 256][pix 4096] bf16 (plane, matches preds_T flat index)
// Wsw layout: [cg 16][ct 4][d 1152][j 8] bf16 ; d = tap*128 + sc*64 + cihalf*32 + colow
// part layout: [slot 96][bid 512] fp32 ; slot: 0..7 pp, 8..15 tt, 16..79 pt(i*8+j)

__device__ __forceinline__ u16 f2b(float f) {
  unsigned u = __builtin_bit_cast(unsigned, f);
  return (u16)((u + 0x7FFFu + ((u >> 16) & 1u)) >> 16);
}
__device__ __forceinline__ float b2f(u16 b) {
  return __builtin_bit_cast(float, ((unsigned)b) << 16);
}

typedef const __attribute__((address_space(1))) unsigned int* gptr_t;
typedef __attribute__((address_space(3))) unsigned int* sptr_t;

// ---------------------------------------------------------------------------
// k1: 1x1 conv + checkerboard mask (fp32 math), swizzled bf16 out.
// ---------------------------------------------------------------------------
__global__ __launch_bounds__(256) void k1(const float* __restrict__ pS,
    const float* __restrict__ Wa, const float* __restrict__ ba,
    u16* __restrict__ mk)
{
  __shared__ float wl[1024];   // [ci 128][k 8]
  int b = blockIdx.x;
  int pb = b & 3, cog = (b >> 2) & 31, n = b >> 7;
  int t = threadIdx.x;
  for (int i = t; i < 1024; i += 256) {
    int ci = i >> 3, k = i & 7;
    wl[i] = Wa[cog * 1024 + k * 128 + ci];
  }
  __syncthreads();

  int pix0 = pb * 1024 + t * 4;
  const float* sp = pS + (((size_t)n * 128) << 12) + pix0;

  float acc[8][4];
  #pragma unroll
  for (int k = 0; k < 8; ++k)
    #pragma unroll
    for (int q = 0; q < 4; ++q) acc[k][q] = 0.f;

  for (int ci = 0; ci < 128; ++ci) {
    float4 s = *(const float4*)(sp + ((size_t)ci << 12));
    float4 w0 = *(const float4*)(wl + ci * 8);
    float4 w1 = *(const float4*)(wl + ci * 8 + 4);
    float wv[8] = {w0.x, w0.y, w0.z, w0.w, w1.x, w1.y, w1.z, w1.w};
    #pragma unroll
    for (int k = 0; k < 8; ++k) {
      acc[k][0] += s.x * wv[k];
      acc[k][1] += s.y * wv[k];
      acc[k][2] += s.z * wv[k];
      acc[k][3] += s.w * wv[k];
    }
  }

  float bias[8];
  #pragma unroll
  for (int k = 0; k < 8; ++k) bias[k] = ba[cog * 8 + k];
  int h = pix0 >> 6, w = pix0 & 63;
  u16* base = mk + (size_t)n * NSTRIDE + (size_t)cog * PLANE8
              + ((size_t)(h + 1) * 66 + (w + 1)) * 8;
  #pragma unroll
  for (int q = 0; q < 4; ++q) {
    float msk = (float)((h + w + q) & 1);
    short8 v;
    #pragma unroll
    for (int k = 0; k < 8; ++k)
      v[k] = (short)f2b((acc[k][q] + bias[k]) * msk);
    *(short8*)(base + q * 8) = v;
  }
}

// ---------------------------------------------------------------------------
// kwc2z: blocks 0..575 convert/swizzle both 3x3 weight tensors;
// blocks 576..1087 zero the halo borders of the 512 masked/t1 planes
// (replaces the 35.7 MB memset with 2.1 MB of targeted stores).
// ---------------------------------------------------------------------------
__global__ __launch_bounds__(256) void kwc2z(const float* __restrict__ W1,
    const float* __restrict__ W2, u16* __restrict__ D1, u16* __restrict__ D2,
    u16* __restrict__ planes)
{
  int b = blockIdx.x, t = threadIdx.x;
  if (b < 576) {
    int cid = b * 256 + t;        // < 147456
    const float* W = W1; u16* D = D1;
    if (cid >= 73728) { W = W2; D = D2; cid -= 73728; }
    int d = cid % 1152, ctcg = cid / 1152;
    int ct = ctcg & 3, cg = ctcg >> 2;
    int colow = d & 31, cihalf = (d >> 5) & 1, sc = (d >> 6) & 1, tap = d >> 7;
    int co = ct * 64 + sc * 32 + colow;
    short8 v;
    #pragma unroll
    for (int jj = 0; jj < 8; ++jj) {
      int ci = cg * 16 + cihalf * 8 + jj;
      v[jj] = (short)f2b(W[((size_t)(co * 256 + ci)) * 9 + tap]);
    }
    *(short8*)&D[(size_t)cid * 8] = v;
  } else {
    int p = b - 576;              // plane 0..511
    u16* pb = planes + (size_t)p * PLANE8;
    short8 z = {0, 0, 0, 0, 0, 0, 0, 0};
    for (int c = t; c < 260; c += 256) {
      int row, col;
      if (c < 66)       { row = 0;  col = c; }
      else if (c < 132) { row = 65; col = c - 66; }
      else if (c < 196) { row = 1 + (c - 132); col = 0; }
      else              { row = 1 + (c - 196); col = 65; }
      *(short8*)(pb + (row * 66 + col) * 8) = z;
    }
  }
}

// ---------------------------------------------------------------------------
// kconv: 3x3 conv 256->256, bf16 MFMA implicit GEMM, 2co x 4pix per wave.
// grid 512 = n(8) x ct(4) x rowtile(16); block 128 thr = 2 waves.
// (R5 structure — best measured variant: LDS-staged weights, 2 barriers/cg.)
// MODE 0: +bias, relu, swizzled padded store (gen1)
// MODE 1: +bias, LDS-transpose, plane store [n][co][4096] (gen2)
// ---------------------------------------------------------------------------
template <int MODE>
__global__ __launch_bounds__(128) void kconv(
    const u16* __restrict__ IN, const u16* __restrict__ WS,
    const float* __restrict__ bg, u16* __restrict__ OUT)
{
  __shared__ __align__(16) u16 Lin[896 * 8];    // 14336 B
  __shared__ __align__(16) u16 Lw[1152 * 8];    // 18432 B

  int b = blockIdx.x;
  int rt = b & 15, ct = (b >> 4) & 3, n = b >> 6;
  int h0 = rt * 4;
  int t = threadIdx.x;
  int wid = t >> 6, lane = t & 63;
  int hf = lane >> 5, ml = lane & 31;

  // Input staging: 14 segs (2 halves x 7), 7 per wave. Tail over-read of s=6
  // stays inside d_ws; garbage LDS chunks (>=396 per half) never read.
  int in_goff[7], lds_off[7];
  #pragma unroll
  for (int k = 0; k < 7; ++k) {
    int seg = 2 * k + wid;
    int half = seg >= 7 ? 1 : 0;
    int s = seg - half * 7;
    in_goff[k] = half * PLANE8 + (h0 * 66 + s * 64 + lane) * 8;
    lds_off[k] = (half * 448 + s * 64) * 8;
  }

  const u16* inb = IN + (size_t)n * NSTRIDE;
  const u16* wg  = WS + (size_t)ct * 1152 * 8;

  floatx16 acc[2][2][2];   // [row r][colhalf s][co-sub q]
  #pragma unroll
  for (int r = 0; r < 2; ++r)
    #pragma unroll
    for (int s = 0; s < 2; ++s)
      #pragma unroll
      for (int q = 0; q < 2; ++q)
        #pragma unroll
        for (int i = 0; i < 16; ++i) acc[r][s][q][i] = 0.f;

  const short8* LinV = (const short8*)Lin;
  const short8* LwV  = (const short8*)Lw;

  for (int cg = 0; cg < 16; ++cg) {
    // ---- stage weights: 18 segs, 9 per wave ----
    #pragma unroll
    for (int k = 0; k < 9; ++k) {
      int sidx = wid + 2 * k;
      const u16* src = wg + (size_t)cg * 36864 + (size_t)(sidx * 64 + lane) * 8;
      __builtin_amdgcn_global_load_lds((gptr_t)(const void*)src,
                                       (sptr_t)(void*)(Lw + sidx * 512), 16, 0, 0);
    }
    // ---- stage input: 14 segs, 7 per wave ----
    #pragma unroll
    for (int k = 0; k < 7; ++k) {
      const u16* src = inb + (size_t)cg * 69696 + in_goff[k];
      __builtin_amdgcn_global_load_lds((gptr_t)(const void*)src,
                                       (sptr_t)(void*)(Lin + lds_off[k]), 16, 0, 0);
    }
    __syncthreads();

    #pragma unroll
    for (int dr = 0; dr < 3; ++dr) {
      int r0 = hf * 448 + (2 * wid + dr) * 66;       // input row for out-row r=0
      int r1 = r0 + 66;                              // r=1
      #pragma unroll
      for (int dc = 0; dc < 3; ++dc) {
        int tap = dr * 3 + dc;
        short8 w0 = LwV[tap * 128 + lane];
        short8 w1 = LwV[tap * 128 + 64 + lane];
        short8 i00 = LinV[r0 + ml + dc];
        short8 i01 = LinV[r0 + 32 + ml + dc];
        short8 i10 = LinV[r1 + ml + dc];
        short8 i11 = LinV[r1 + 32 + ml + dc];
        acc[0][0][0] = __builtin_amdgcn_mfma_f32_32x32x16_bf16(i00, w0, acc[0][0][0], 0, 0, 0);
        acc[0][0][1] = __builtin_amdgcn_mfma_f32_32x32x16_bf16(i00, w1, acc[0][0][1], 0, 0, 0);
        acc[0][1][0] = __builtin_amdgcn_mfma_f32_32x32x16_bf16(i01, w0, acc[0][1][0], 0, 0, 0);
        acc[0][1][1] = __builtin_amdgcn_mfma_f32_32x32x16_bf16(i01, w1, acc[0][1][1], 0, 0, 0);
        acc[1][0][0] = __builtin_amdgcn_mfma_f32_32x32x16_bf16(i10, w0, acc[1][0][0], 0, 0, 0);
        acc[1][0][1] = __builtin_amdgcn_mfma_f32_32x32x16_bf16(i10, w1, acc[1][0][1], 0, 0, 0);
        acc[1][1][0] = __builtin_amdgcn_mfma_f32_32x32x16_bf16(i11, w0, acc[1][1][0], 0, 0, 0);
        acc[1][1][1] = __builtin_amdgcn_mfma_f32_32x32x16_bf16(i11, w1, acc[1][1][1], 0, 0, 0);
      }
    }
    __syncthreads();
  }

  float bias0 = bg[ct * 64 + ml];        // q=0
  float bias1 = bg[ct * 64 + 32 + ml];   // q=1

  if (MODE == 0) {
    u16* ob = OUT + (size_t)n * NSTRIDE;
    int co0 = ct * 64 + ml, co1 = co0 + 32;
    int cb0 = ((co0 >> 4) * 2 + ((co0 >> 3) & 1)) * PLANE8 + (co0 & 7);
    int cb1 = ((co1 >> 4) * 2 + ((co1 >> 3) & 1)) * PLANE8 + (co1 & 7);
    #pragma unroll
    for (int r = 0; r < 2; ++r) {
      int rowoff = (h0 + 2 * wid + r + 1) * 66 + 1;
      #pragma unroll
      for (int reg = 0; reg < 16; ++reg) {
        int m = (reg & 3) + 8 * (reg >> 2) + 4 * hf;
        float v;
        v = acc[r][0][0][reg] + bias0; v = fmaxf(v, 0.f); ob[cb0 + (rowoff + m) * 8] = f2b(v);
        v = acc[r][0][1][reg] + bias1; v = fmaxf(v, 0.f); ob[cb1 + (rowoff + m) * 8] = f2b(v);
        v = acc[r][1][0][reg] + bias0; v = fmaxf(v, 0.f); ob[cb0 + (rowoff + 32 + m) * 8] = f2b(v);
        v = acc[r][1][1][reg] + bias1; v = fmaxf(v, 0.f); ob[cb1 + (rowoff + 32 + m) * 8] = f2b(v);
      }
    }
  } else {
    // LDS transpose -> plane [n][co][4096]; per-wave plane 64co x 64col, stride 68.
    u16* plane = (wid == 0) ? Lin : Lw;
    #pragma unroll
    for (int r = 0; r < 2; ++r) {
      __syncthreads();
      #pragma unroll
      for (int reg = 0; reg < 16; ++reg) {
        int m = (reg & 3) + 8 * (reg >> 2) + 4 * hf;
        plane[ml * 68 + m]              = f2b(acc[r][0][0][reg] + bias0);
        plane[(32 + ml) * 68 + m]       = f2b(acc[r][0][1][reg] + bias1);
        plane[ml * 68 + 32 + m]         = f2b(acc[r][1][0][reg] + bias0);
        plane[(32 + ml) * 68 + 32 + m]  = f2b(acc[r][1][1][reg] + bias1);
      }
      __syncthreads();
      const u16* row = plane + lane * 68;   // co_local = lane
      __align__(16) u16 tmp[64];
      #pragma unroll
      for (int k2 = 0; k2 < 16; ++k2)
        *(ushort4*)(tmp + k2 * 4) = *(const ushort4*)(row + k2 * 4);
      u16* gdst = OUT + (size_t)n * 1048576 + (size_t)(ct * 64 + lane) * 4096
                  + (h0 + 2 * wid + r) * 64;
      #pragma unroll
      for (int k2 = 0; k2 < 8; ++k2)
        *(ushort8*)(gdst + k2 * 8) = *(const ushort8*)(tmp + k2 * 8);
    }
  }
}

// ---------------------------------------------------------------------------
// kbmc: fused reduction over d (plane layouts match). No atomics.
// ---------------------------------------------------------------------------
__global__ __launch_bounds__(256) void kbmc(const u16* __restrict__ t2,
    const float* __restrict__ pT, float* __restrict__ part)
{
  int t = threadIdx.x, lane = t & 63, role = t >> 6;
  int ih = role >> 1, nh = role & 1;
  int bid = blockIdx.x;

  float pt[4][4], pp[4], tt[4];
  #pragma unroll
  for (int i = 0; i < 4; ++i) {
    pp[i] = 0.f; tt[i] = 0.f;
    #pragma unroll
    for (int j = 0; j < 4; ++j) pt[i][j] = 0.f;
  }

  const float* pb = pT + ((size_t)ih * 4) * 1048576;
  const u16*   tb = t2 + ((size_t)nh * 4) * 1048576;

  for (int k = 0; k < 8; ++k) {
    size_t d0 = ((size_t)(bid * 512 + k * 64 + lane)) * 4;
    float4 p[4], tf[4];
    #pragma unroll
    for (int i = 0; i < 4; ++i)
      p[i] = *(const float4*)(pb + (size_t)i * 1048576 + d0);
    #pragma unroll
    for (int j = 0; j < 4; ++j) {
      ushort4 tv = *(const ushort4*)(tb + (size_t)j * 1048576 + d0);
      tf[j] = make_float4(b2f(tv.x), b2f(tv.y), b2f(tv.z), b2f(tv.w));
    }
    if (nh == 0) {
      #pragma unroll
      for (int i = 0; i < 4; ++i)
        pp[i] += p[i].x * p[i].x + p[i].y * p[i].y + p[i].z * p[i].z + p[i].w * p[i].w;
    }
    if (ih == 0) {
      #pragma unroll
      for (int j = 0; j < 4; ++j)
        tt[j] += tf[j].x * tf[j].x + tf[j].y * tf[j].y + tf[j].z * tf[j].z + tf[j].w * tf[j].w;
    }
    #pragma unroll
    for (int i = 0; i < 4; ++i)
      #pragma unroll
      for (int j = 0; j < 4; ++j)
        pt[i][j] += p[i].x * tf[j].x + p[i].y * tf[j].y
                  + p[i].z * tf[j].z + p[i].w * tf[j].w;
  }

  #pragma unroll
  for (int m = 1; m < 64; m <<= 1) {
    #pragma unroll
    for (int i = 0; i < 4; ++i) {
      pp[i] += __shfl_xor(pp[i], m);
      tt[i] += __shfl_xor(tt[i], m);
      #pragma unroll
      for (int j = 0; j < 4; ++j) pt[i][j] += __shfl_xor(pt[i][j], m);
    }
  }
  if (lane == 0) {
    #pragma unroll
    for (int i = 0; i < 4; ++i)
      #pragma unroll
      for (int j = 0; j < 4; ++j)
        part[(size_t)(16 + (ih * 4 + i) * 8 + (nh * 4 + j)) * 512 + bid] = pt[i][j];
    if (nh == 0) {
      #pragma unroll
      for (int i = 0; i < 4; ++i) part[(size_t)(ih * 4 + i) * 512 + bid] = pp[i];
    }
    if (ih == 0) {
      #pragma unroll
      for (int j = 0; j < 4; ++j) part[(size_t)(8 + nh * 4 + j) * 512 + bid] = tt[j];
    }
  }
}

// ---------------------------------------------------------------------------
// kredfin: single block, 640 active threads. 8 threads per slot reduce
// part[s][0..512); then lanes 0..63 do the 8x8 logsumexp.
// ---------------------------------------------------------------------------
__global__ __launch_bounds__(1024) void kredfin(const float* __restrict__ part,
                                                float* __restrict__ out)
{
  __shared__ float ac[80];
  int t = threadIdx.x;
  if (t < 640) {
    int s = t >> 3, q = t & 7;
    float v = 0.f;
    #pragma unroll 8
    for (int k = 0; k < 64; ++k)
      v += part[(size_t)s * 512 + q + k * 8];
    #pragma unroll
    for (int m = 1; m < 8; m <<= 1) v += __shfl_xor(v, m);
    if (q == 0) ac[s] = v;
  }
  __syncthreads();
  if (t < 64) {
    int i = t >> 3, j = t & 7;
    double pp = ac[i];
    double tt = ac[8 + j];
    double pt = ac[16 + i * 8 + j];
    double logit = -0.5 * (pp + tt - 2.0 * pt) / 64.0;
    double m = logit;
    #pragma unroll
    for (int s = 1; s < 8; s <<= 1) {
      double o = __shfl_xor(m, s);
      m = o > m ? o : m;
    }
    double e = exp(logit - m);
    #pragma unroll
    for (int s = 1; s < 8; s <<= 1) e += __shfl_xor(e, s);
    double lse = m + log(e);
    double term = (j == i) ? (lse - logit) : 0.0;
    #pragma unroll
    for (int s = 1; s < 64; s <<= 1) term += __shfl_xor(term, s);
    if (t == 0) {
      double ce = term / 8.0;
      out[0] = (float)(ce * (2.0 * 64.0) / 8.0 * 2e-05);
    }
  }
}

// ---------------------------------------------------------------------------
extern "C" void kernel_launch(void* const* d_in, const int* in_sizes, int n_in,
                              void* d_out, int out_size, void* d_ws, size_t ws_size,
                              hipStream_t stream)
{
  const float* preds_S = (const float*)d_in[0];
  const float* preds_T = (const float*)d_in[1];
  const float* W_align = (const float*)d_in[2];
  const float* b_align = (const float*)d_in[3];
  const float* W_gen1  = (const float*)d_in[4];
  const float* b_gen1  = (const float*)d_in[5];
  const float* W_gen2  = (const float*)d_in[6];
  const float* b_gen2  = (const float*)d_in[7];
  float* out = (float*)d_out;

  char* wsb = (char*)d_ws;
  u16* masked = (u16*)wsb;                          // 17,842,176 B (swizzled padded)
  u16* t1     = (u16*)(wsb + 17842176);             // 17,842,176 B (swizzled padded)
  u16* t2p    = (u16*)(wsb + 35684352);             // 16,777,216 B (plane [n][co][pix])
  u16* Wsw1   = (u16*)(wsb + 52461568);             //  1,179,648 B
  u16* Wsw2   = (u16*)(wsb + 53641216);             //  1,179,648 B
  float* part = (float*)(wsb + 54820864);           //    196,608 B [96][512]

  // No memset: kwc2z's tail blocks zero the 512 plane borders (masked+t1
  // are contiguous); every interior cell is overwritten by k1/kconv<0>.
  kwc2z<<<1088, 256, 0, stream>>>(W_gen1, W_gen2, Wsw1, Wsw2, masked);
  k1<<<1024, 256, 0, stream>>>(preds_S, W_align, b_align, masked);
  kconv<0><<<512, 128, 0, stream>>>(masked, Wsw1, b_gen1, t1);    // relu -> t1
  kconv<1><<<512, 128, 0, stream>>>(t1, Wsw2, b_gen2, t2p);       // plane -> t2
  kbmc<<<512, 256, 0, stream>>>(t2p, preds_T, part);
  kredfin<<<1, 1024, 0, stream>>>(part, out);
}